// Round 5
// baseline (51.261 us; speedup 1.0000x reference)
//
#include <hip/hip_runtime.h>
#include <math.h>

#define HWPIX 3136   // 56*56
#define NC    256
#define NCNEW 128
#define NH    16     // C/R

// ---------------------------------------------------------------------------
// numpy pairwise block sum (8 <= n <= 128), exact replication of
// numpy's pairwise_sum_FLOAT block: 8 accumulators seeded with a[0..7],
// unrolled adds, fixed combine bracketing, sequential tail.
// ---------------------------------------------------------------------------
__device__ __forceinline__ float np_block_sum(const float* __restrict__ a, int n) {
    float r0=a[0],r1=a[1],r2=a[2],r3=a[3],r4=a[4],r5=a[5],r6=a[6],r7=a[7];
    int i = 8;
    const int lim = n - (n & 7);
    for (; i < lim; i += 8) {
        r0 += a[i+0]; r1 += a[i+1]; r2 += a[i+2]; r3 += a[i+3];
        r4 += a[i+4]; r5 += a[i+5]; r6 += a[i+6]; r7 += a[i+7];
    }
    float res = ((r0 + r1) + (r2 + r3)) + ((r4 + r5) + (r6 + r7));
    for (; i < n; ++i) res += a[i];
    return res;
}

// ---------------------------------------------------------------------------
// Kernel 1: per-(b,c) mean, bitwise np.float32 mean. 4 planes per block,
// one wave per plane; each wave is fully independent (own LDS segment,
// no __syncthreads — same-wave ds_write->ds_read ordering is lgkmcnt).
// Straight-line staging: 13 float4 loads in flight before any LDS write.
// Combine: np pairwise tree = leaf blocks + xor-butterfly (bit-exact).
// ---------------------------------------------------------------------------
__global__ __launch_bounds__(256) void k_mean(const float* __restrict__ x,
                                              float* __restrict__ s) {
    const int w = threadIdx.x >> 6;   // wave 0..3
    const int t = threadIdx.x & 63;   // lane
    const int plane = blockIdx.x * 4 + w;  // b*256 + c
    __shared__ float pl[4][HWPIX];

    const float4* src4 = reinterpret_cast<const float4*>(x + (size_t)plane * HWPIX);

    float4 va[13];
    #pragma unroll
    for (int i = 0; i < 12; ++i) va[i] = src4[i * 64 + t];
    {   // tail: 16 real float4s; clamp source so the full wave issues loads
        int idx = 768 + t; if (idx > 783) idx = 783;
        va[12] = src4[idx];
    }
    float* pw = pl[w];
    #pragma unroll
    for (int i = 0; i < 12; ++i)
        *reinterpret_cast<float4*>(&pw[(i * 64 + t) * 4]) = va[i];
    if (t < 16)
        *reinterpret_cast<float4*>(&pw[(768 + t) * 4]) = va[12];

    // leaf t: chunk m = t/2 covers [98m, 98m+98); even leaf 48, odd leaf 50
    const int m    = t >> 1;
    const int base = 98 * m + ((t & 1) ? 48 : 0);
    const int n    = (t & 1) ? 50 : 48;
    float v = np_block_sum(pw + base, n);

    // exact pairwise tree over the 64 leaves via xor-butterfly
    #pragma unroll
    for (int mask = 1; mask <= 32; mask <<= 1)
        v += __shfl_xor(v, mask, 64);

    if (t == 0) s[plane] = v / 3136.0f;   // f32 true divide, like np.mean
}

// ---------------------------------------------------------------------------
// Kernel 2: f32 MLP (sequential-k FMA chains = BLAS sgemm microkernel
// order), correctly-rounded f32 exp, exact f32 rank with index tie-break.
// ---------------------------------------------------------------------------
__global__ __launch_bounds__(256) void k_mlp_topk(const float* __restrict__ s,
                                                  const float* __restrict__ w1,
                                                  const float* __restrict__ b1,
                                                  const float* __restrict__ w2,
                                                  const float* __restrict__ b2,
                                                  float* __restrict__ gate_out,
                                                  int* __restrict__ idx_out) {
    const int b = blockIdx.x;
    const int c = threadIdx.x;

    __shared__ float sh_s[NC];
    __shared__ float sh_h[NH];
    __shared__ float sh_g[NC];

    sh_s[c] = s[b * NC + c];
    __syncthreads();

    if (c < NH) {
        float acc = 0.0f;
        for (int k = 0; k < NC; ++k)
            acc = fmaf(sh_s[k], w1[c * NC + k], acc);   // sgemm: seq-k FMA
        float hp = acc + b1[c];                          // bias added after
        sh_h[c] = fmaxf(hp, 0.0f);                       // relu
    }
    __syncthreads();

    float acc = 0.0f;
    #pragma unroll
    for (int j = 0; j < NH; ++j)
        acc = fmaf(sh_h[j], w2[c * NH + j], acc);
    const float z  = acc + b2[c];
    const float ef = (float)exp((double)(-z));  // ~correctly-rounded f32 exp
    const float g  = 1.0f / (1.0f + ef);        // f32 add, f32 div
    sh_g[c] = g;
    __syncthreads();

    // rank by exact f32 gate, descending, stable (lower index first on tie)
    int r = 0;
    for (int k = 0; k < NC; ++k) {
        const float gk = sh_g[k];
        r += (gk > g) || (gk == g && k < c);
    }
    if (r < NCNEW) {
        gate_out[b * NCNEW + r] = g;
        idx_out[b * NCNEW + r]  = c;
    }
}

// ---------------------------------------------------------------------------
// Kernel 3: gather selected channel planes and scale by gate (f32 mul,
// bitwise = reference's final multiply). 4 planes per block, one wave per
// plane; 13 float4 loads in flight per lane before any store.
// ---------------------------------------------------------------------------
__global__ __launch_bounds__(256) void k_gather(const float* __restrict__ x,
                                                const float* __restrict__ gate,
                                                const int* __restrict__ idx,
                                                float* __restrict__ out) {
    const int w = threadIdx.x >> 6;   // wave 0..3
    const int t = threadIdx.x & 63;   // lane
    const int op = blockIdx.x * 4 + w;   // output plane: b*128 + j
    const int b = op >> 7;
    const int c = idx[op];
    const float g = gate[op];

    const float4* src = reinterpret_cast<const float4*>(
        x + ((size_t)(b * NC + c)) * HWPIX);
    float4* dst = reinterpret_cast<float4*>(out + (size_t)op * HWPIX);

    float4 va[13];
    #pragma unroll
    for (int i = 0; i < 12; ++i) va[i] = src[i * 64 + t];
    {   int ii = 768 + t; if (ii > 783) ii = 783;
        va[12] = src[ii];
    }
    #pragma unroll
    for (int i = 0; i < 12; ++i) {
        float4 v = va[i];
        v.x *= g; v.y *= g; v.z *= g; v.w *= g;
        dst[i * 64 + t] = v;
    }
    if (t < 16) {
        float4 v = va[12];
        v.x *= g; v.y *= g; v.z *= g; v.w *= g;
        dst[768 + t] = v;
    }
}

// ---------------------------------------------------------------------------
extern "C" void kernel_launch(void* const* d_in, const int* in_sizes, int n_in,
                              void* d_out, int out_size, void* d_ws, size_t ws_size,
                              hipStream_t stream) {
    const float* x  = (const float*)d_in[0];
    const float* w1 = (const float*)d_in[1];
    const float* b1 = (const float*)d_in[2];
    const float* w2 = (const float*)d_in[3];
    const float* b2 = (const float*)d_in[4];
    float* out = (float*)d_out;

    // workspace: s (8192 f32) | gate (4096 f32) | idx (4096 i32)
    char* ws = (char*)d_ws;
    float* s_ws   = (float*)ws;                     // 32768 B
    float* gate_w = (float*)(ws + 32768);           // 16384 B
    int*   idx_w  = (int*)(ws + 32768 + 16384);     // 16384 B

    k_mean<<<2048, 256, 0, stream>>>(x, s_ws);
    k_mlp_topk<<<32, 256, 0, stream>>>(s_ws, w1, b1, w2, b2, gate_w, idx_w);
    k_gather<<<1024, 256, 0, stream>>>(x, gate_w, idx_w, out);
}

// Round 6
// 48.550 us; speedup vs baseline: 1.0558x; 1.0558x over previous
//
#include <hip/hip_runtime.h>
#include <math.h>

#define HWPIX 3136   // 56*56
#define NC    256
#define NCNEW 128
#define NH    16     // C/R

// ---------------------------------------------------------------------------
// numpy pairwise block sum (8 <= n <= 128), exact replication of
// numpy's pairwise_sum_FLOAT block: 8 accumulators seeded with a[0..7],
// unrolled adds, fixed combine bracketing, sequential tail.
// ---------------------------------------------------------------------------
__device__ __forceinline__ float np_block_sum(const float* __restrict__ a, int n) {
    float r0=a[0],r1=a[1],r2=a[2],r3=a[3],r4=a[4],r5=a[5],r6=a[6],r7=a[7];
    int i = 8;
    const int lim = n - (n & 7);
    for (; i < lim; i += 8) {
        r0 += a[i+0]; r1 += a[i+1]; r2 += a[i+2]; r3 += a[i+3];
        r4 += a[i+4]; r5 += a[i+5]; r6 += a[i+6]; r7 += a[i+7];
    }
    float res = ((r0 + r1) + (r2 + r3)) + ((r4 + r5) + (r6 + r7));
    for (; i < n; ++i) res += a[i];
    return res;
}

// ---------------------------------------------------------------------------
// Kernel 1 (round-4 best): per-(b,c) mean, bitwise np.float32 mean.
// One 64-thread block per plane, straight-line staging (13 loads in
// flight), np pairwise tree = leaf blocks + xor-butterfly (bit-exact).
// ---------------------------------------------------------------------------
__global__ __launch_bounds__(64) void k_mean(const float* __restrict__ x,
                                             float* __restrict__ s) {
    const int plane = blockIdx.x;  // b*256 + c
    const int t = threadIdx.x;
    __shared__ float pl[HWPIX];

    const float4* src4 = reinterpret_cast<const float4*>(x + (size_t)plane * HWPIX);

    float4 va[13];
    #pragma unroll
    for (int i = 0; i < 12; ++i) va[i] = src4[i * 64 + t];
    {   // tail: 16 real float4s; clamp source so the full wave issues loads
        int idx = 768 + t; if (idx > 783) idx = 783;
        va[12] = src4[idx];
    }
    #pragma unroll
    for (int i = 0; i < 12; ++i)
        *reinterpret_cast<float4*>(&pl[(i * 64 + t) * 4]) = va[i];
    if (t < 16)
        *reinterpret_cast<float4*>(&pl[(768 + t) * 4]) = va[12];
    __syncthreads();

    // leaf t: chunk m = t/2 covers [98m, 98m+98); even leaf 48, odd leaf 50
    const int m    = t >> 1;
    const int base = 98 * m + ((t & 1) ? 48 : 0);
    const int n    = (t & 1) ? 50 : 48;
    float v = np_block_sum(pl + base, n);

    // exact pairwise tree over the 64 leaves via xor-butterfly
    #pragma unroll
    for (int mask = 1; mask <= 32; mask <<= 1)
        v += __shfl_xor(v, mask, 64);

    if (t == 0) s[plane] = v / 3136.0f;   // f32 true divide, like np.mean
}

// ---------------------------------------------------------------------------
// Kernel 2: f32 MLP + sigmoid + exact stable rank. SAME arithmetic order
// as the passing version (seq-k fmaf chains, cr-exp sigmoid, stable rank)
// but all operands staged into LDS with coalesced float4 loads first:
// the old version's 16-lane chain read w1 scalar from GLOBAL (up to
// 256 x ~200cy serial = ~20us on one wave). w1 is stored transposed so
// the 16 chain lanes read consecutive LDS words (conflict-free).
// ---------------------------------------------------------------------------
__global__ __launch_bounds__(256) void k_mlp_topk(const float* __restrict__ s,
                                                  const float* __restrict__ w1,
                                                  const float* __restrict__ b1,
                                                  const float* __restrict__ w2,
                                                  const float* __restrict__ b2,
                                                  float* __restrict__ gate_out,
                                                  int* __restrict__ idx_out) {
    const int b   = blockIdx.x;
    const int tid = threadIdx.x;

    __shared__ float sh_s[NC];
    __shared__ float sh_w1t[NC][NH];   // transposed: [k][j]  (16 KB)
    __shared__ float sh_w2[NC * NH];   // row-major [c][j]    (16 KB)
    __shared__ float sh_h[NH];
    __shared__ float sh_g[NC];

    // prefetch biases into registers (hide global latency under staging)
    const float bias2 = b2[tid];
    float bias1 = 0.0f;
    if (tid < NH) bias1 = b1[tid];

    // coalesced staging: w1 + w2 are 4096 floats = 1024 float4 each
    #pragma unroll
    for (int i = 0; i < 4; ++i) {
        const int f4 = i * 256 + tid;
        float4 v = reinterpret_cast<const float4*>(w1)[f4];
        const int base = f4 * 4;        // flat = j*256 + k
        const int j = base >> 8;
        const int k = base & 255;
        sh_w1t[k+0][j] = v.x; sh_w1t[k+1][j] = v.y;
        sh_w1t[k+2][j] = v.z; sh_w1t[k+3][j] = v.w;
        reinterpret_cast<float4*>(sh_w2)[f4] =
            reinterpret_cast<const float4*>(w2)[f4];
    }
    if (tid < 64)
        reinterpret_cast<float4*>(sh_s)[tid] =
            reinterpret_cast<const float4*>(s + b * NC)[tid];
    __syncthreads();

    if (tid < NH) {
        float acc = 0.0f;
        #pragma unroll 16
        for (int k = 0; k < NC; ++k)
            acc = fmaf(sh_s[k], sh_w1t[k][tid], acc);   // exact seq-k chain
        float hp = acc + bias1;                          // bias added after
        sh_h[tid] = fmaxf(hp, 0.0f);                     // relu
    }
    __syncthreads();

    float acc = 0.0f;
    #pragma unroll
    for (int j = 0; j < NH; ++j)
        acc = fmaf(sh_h[j], sh_w2[tid * NH + j], acc);
    const float z  = acc + bias2;
    const float ef = (float)exp((double)(-z));  // ~correctly-rounded f32 exp
    const float g  = 1.0f / (1.0f + ef);        // f32 add, f32 div
    sh_g[tid] = g;
    __syncthreads();

    // rank by exact f32 gate, descending, stable (lower index first on tie)
    int r = 0;
    #pragma unroll 8
    for (int k = 0; k < NC; ++k) {
        const float gk = sh_g[k];
        r += (gk > g) || (gk == g && k < tid);
    }
    if (r < NCNEW) {
        gate_out[b * NCNEW + r] = g;
        idx_out[b * NCNEW + r]  = tid;
    }
}

// ---------------------------------------------------------------------------
// Kernel 3 (round-4 best): gather selected channel planes, scale by gate
// (f32 mul, bitwise = reference). 256 threads per output plane.
// ---------------------------------------------------------------------------
__global__ __launch_bounds__(256) void k_gather(const float* __restrict__ x,
                                                const float* __restrict__ gate,
                                                const int* __restrict__ idx,
                                                float* __restrict__ out) {
    const int bid = blockIdx.x;      // b*128 + j
    const int b = bid >> 7;
    const int c = idx[bid];
    const float g = gate[bid];

    const float4* src = reinterpret_cast<const float4*>(
        x + ((size_t)(b * NC + c)) * HWPIX);
    float4* dst = reinterpret_cast<float4*>(out + (size_t)bid * HWPIX);

    const int t = threadIdx.x;
    float4 v;
    v = src[t];       v.x *= g; v.y *= g; v.z *= g; v.w *= g; dst[t]       = v;
    v = src[t + 256]; v.x *= g; v.y *= g; v.z *= g; v.w *= g; dst[t + 256] = v;
    v = src[t + 512]; v.x *= g; v.y *= g; v.z *= g; v.w *= g; dst[t + 512] = v;
    if (t < 16) {
        v = src[t + 768]; v.x *= g; v.y *= g; v.z *= g; v.w *= g; dst[t + 768] = v;
    }
}

// ---------------------------------------------------------------------------
extern "C" void kernel_launch(void* const* d_in, const int* in_sizes, int n_in,
                              void* d_out, int out_size, void* d_ws, size_t ws_size,
                              hipStream_t stream) {
    const float* x  = (const float*)d_in[0];
    const float* w1 = (const float*)d_in[1];
    const float* b1 = (const float*)d_in[2];
    const float* w2 = (const float*)d_in[3];
    const float* b2 = (const float*)d_in[4];
    float* out = (float*)d_out;

    // workspace: s (8192 f32) | gate (4096 f32) | idx (4096 i32)
    char* ws = (char*)d_ws;
    float* s_ws   = (float*)ws;                     // 32768 B
    float* gate_w = (float*)(ws + 32768);           // 16384 B
    int*   idx_w  = (int*)(ws + 32768 + 16384);     // 16384 B

    k_mean<<<32 * NC, 64, 0, stream>>>(x, s_ws);
    k_mlp_topk<<<32, 256, 0, stream>>>(s_ws, w1, b1, w2, b2, gate_w, idx_w);
    k_gather<<<32 * NCNEW, 256, 0, stream>>>(x, gate_w, idx_w, out);
}